// Round 6
// baseline (585.670 us; speedup 1.0000x reference)
//
#include <hip/hip_runtime.h>
#include <math.h>

#define BATCH 8192
#define D_G   4611
#define DGP   4624   // padded Wcat row stride (multiple of 16 floats for aligned float4)
#define KN    25
#define KE    28     // padded row: 25 weights, [25]=bias/alpha slot, [26..27]=0

// workspace offsets (floats)
#define WS_WCAT   0        // [25][4624]
#define WS_BCAT   115600   // [4624]  (== row 25 of WS_WCAT at stride DGP — contiguous!)
#define WS_WCATT  120224   // [4611][28]   row d = [w[0..24], bias, 0, 0]
#define WS_M      249344   // [25][25]
#define WS_C      249984   // [25]
#define WS_BB     250016   // [1]
#define WS_PPAD   250048   // [8192][28]   [25] = -q/2
#define WS_Q      479424   // [8192]
#define WS_G2     487616   // [8192]
#define WS_RPAD   495808   // [8192][28]   [25] = -T/2
#define WS_WP2    725184   // [8192] min sq bits (prior->G)
#define WS_WW2    733376   // [8192] min sq bits (G->G, i!=j)
#define WS_ACC    741568   // recon accumulator
#define WS_H1T    741600   // [64][8192]
#define WS_H2T    1265888  // [64][8192]

__device__ inline float eluf(float x) { return x > 0.f ? x : expm1f(x); }

// async global->LDS, 16B per lane. lds dest must be wave-uniform base (+lane*16 implicit).
__device__ __forceinline__ void gload_lds16(const float* g, float* l) {
  __builtin_amdgcn_global_load_lds((const __attribute__((address_space(1))) unsigned int*)g,
                                   (__attribute__((address_space(3))) unsigned int*)l, 16, 0, 0);
}

// dot of a wave-uniform 28-float row (25 weights + bias/alpha at [25]) with per-lane nx[25].
// readfirstlane forces the row pointer scalar -> s_load (SMEM pipe, SGPR-sourced FMAs).
__device__ inline float sdot26(const float* __restrict__ WT, int rowidx, const float* nx) {
  const float* row = WT + (size_t)__builtin_amdgcn_readfirstlane(rowidx) * KE;
  float acc = row[25];
#pragma unroll
  for (int k = 0; k < 25; k++) acc = fmaf(row[k], nx[k], acc);
  return acc;
}

__global__ void k_build(const float* __restrict__ w1W, const float* __restrict__ w1b,
                        const float* __restrict__ b1W, const float* __restrict__ b1b,
                        const float* __restrict__ w2W, const float* __restrict__ w2b,
                        const float* __restrict__ b2W, const float* __restrict__ b2b,
                        const float* __restrict__ w3W, const float* __restrict__ w3b,
                        const float* __restrict__ b3W, const float* __restrict__ b3b,
                        float* ws) {
  int idx = blockIdx.x * 256 + threadIdx.x;
  // folded k_init (grid covers 2*BATCH+1 easily)
  unsigned int* u = (unsigned int*)ws;
  if (idx < BATCH)            u[WS_WP2 + idx] = 0x7F7FFFFFu;
  else if (idx < 2 * BATCH)   u[WS_WW2 + (idx - BATCH)] = 0x7F7FFFFFu;
  else if (idx == 2 * BATCH)  ws[WS_ACC] = 0.f;
  if (idx >= KN * D_G) return;
  int k = idx / D_G;
  int d = idx - k * D_G;
  float wv, bv;
  if (d < 192)       { int c = d;        wv = w1W[k*192  + c]; bv = w1b[c]; }
  else if (d < 256)  { int c = d - 192;  wv = b1W[k*64   + c]; bv = b1b[c]; }
  else if (d < 4352) { int c = d - 256;  wv = w2W[k*4096 + c]; bv = w2b[c]; }
  else if (d < 4416) { int c = d - 4352; wv = b2W[k*64   + c]; bv = b2b[c]; }
  else if (d < 4608) { int c = d - 4416; wv = w3W[k*192  + c]; bv = w3b[c]; }
  else               { int c = d - 4608; wv = b3W[k*3    + c]; bv = b3b[c]; }
  ws[WS_WCAT  + k * DGP + d] = wv;
  ws[WS_WCATT + d * KE  + k] = wv;
  if (k == 0) {
    ws[WS_BCAT + d] = bv;
    ws[WS_WCATT + d * KE + 25] = bv;
    ws[WS_WCATT + d * KE + 26] = 0.f;
    ws[WS_WCATT + d * KE + 27] = 0.f;
  }
}

// M = Wcat Wcat^T (25x25), c = Wcat bcat, bb = |bcat|^2 — shfl-based reduction
__global__ __launch_bounds__(256) void k_M(float* ws) {
  const float* Wc = ws + WS_WCAT;
  const float* bc = ws + WS_BCAT;
  __shared__ float part[4][26];
  int a = blockIdx.x, t = threadIdx.x;
  int wv = t >> 6, l = t & 63;
  if (a < 25) {
    float acc[26];
#pragma unroll
    for (int v = 0; v < 26; v++) acc[v] = 0.f;
    for (int d = t; d < D_G; d += 256) {
      float va = Wc[a * DGP + d];
#pragma unroll
      for (int b = 0; b < 25; b++) acc[b] += va * Wc[b * DGP + d];
      acc[25] += va * bc[d];
    }
#pragma unroll
    for (int v = 0; v < 26; v++) {
      float x = acc[v];
#pragma unroll
      for (int off = 32; off > 0; off >>= 1) x += __shfl_down(x, off, 64);
      if (l == 0) part[wv][v] = x;
    }
    __syncthreads();
    if (t < 26) {
      float s = part[0][t] + part[1][t] + part[2][t] + part[3][t];
      if (t < 25) ws[WS_M + a * 25 + t] = s; else ws[WS_C + a] = s;
    }
  } else {
    float acc = 0.f;
    for (int d = t; d < D_G; d += 256) { float b = bc[d]; acc += b * b; }
#pragma unroll
    for (int off = 32; off > 0; off >>= 1) acc += __shfl_down(acc, off, 64);
    if (l == 0) part[wv][0] = acc;
    __syncthreads();
    if (t == 0) ws[WS_BB] = part[0][0] + part[1][0] + part[2][0] + part[3][0];
  }
}

// PPAD rows, q, g2
__global__ void k_persample(const float* __restrict__ n, float* ws) {
  int j = blockIdx.x * 256 + threadIdx.x;
  if (j >= BATCH) return;
  const float* M  = ws + WS_M;
  const float* cv = ws + WS_C;
  float nr[25];
#pragma unroll
  for (int k = 0; k < 25; k++) nr[k] = n[j * 25 + k];
  float q = 0.f;
  for (int k2 = 0; k2 < 25; k2++) {
    float p = 0.f;
#pragma unroll
    for (int k1 = 0; k1 < 25; k1++) p += nr[k1] * M[k1 * 25 + k2];
    ws[WS_PPAD + j * KE + k2] = p;
    q += p * nr[k2];
  }
  float nc = 0.f;
#pragma unroll
  for (int k = 0; k < 25; k++) nc += nr[k] * cv[k];
  ws[WS_PPAD + j * KE + 25] = -0.5f * q;
  ws[WS_PPAD + j * KE + 26] = 0.f;
  ws[WS_PPAD + j * KE + 27] = 0.f;
  ws[WS_Q  + j] = q;
  ws[WS_G2 + j] = q + 2.f * nc + ws[WS_BB];
}

// RPAD rows: r_i = prior_i @ Wcat^T, [25] = -0.5*(|p_i|^2 - 2 p_i.bcat)
// R1-proven pipeline (93 µs, no spills): double-buffered LDS staged by async
// global_load_lds, prior values register-double-buffered (2-deep only — 3-deep
// spills, see R4), one __syncthreads per chunk.
// SPILL TRIPWIRE: WRITE_SIZE must stay ~0.9 MB; any MB-scale growth = scratch.
__global__ __launch_bounds__(256, 2) void k_prior(const float* __restrict__ prior, float* ws) {
  __shared__ float wlds[2][26 * 256 + 512];   // 28 rows x 256 floats per buffer (rows 26/27 unused pad)
  const float* wc = ws + WS_WCAT;   // rows 0..24 Wcat, row 25 = bcat (stride DGP)
  const float* bc = ws + WS_BCAT;
  int t = threadIdx.x;
  int wv = t >> 6, l = t & 63;
  int i0 = (blockIdx.x * 4 + wv) * 4;  // 4 rows per wave
  const float* pr0 = prior + (size_t)i0 * D_G;

  float racc[4][25];
  float sacc[4], p2acc[4];
#pragma unroll
  for (int r = 0; r < 4; r++) {
    sacc[r] = 0.f; p2acc[r] = 0.f;
#pragma unroll
    for (int k = 0; k < 25; k++) racc[r][k] = 0.f;
  }

  float pvC[4][4], pvN[4][4];

  // prologue: stage chunk 0 (async) + issue prior loads for chunk 0
#pragma unroll
  for (int u = 0; u < 7; u++) {
    int row = u * 4 + wv;                       // wave-uniform
    if (row < 26)
      gload_lds16(wc + (size_t)row * DGP + 4 * l, &wlds[0][row * 256]);
  }
#pragma unroll
  for (int r = 0; r < 4; r++)
#pragma unroll
    for (int q = 0; q < 4; q++)
      pvN[r][q] = pr0[(size_t)r * D_G + 4 * l + q];

  for (int ch = 0; ch < 18; ++ch) {
    int cur = ch & 1;
    __syncthreads();   // implicit vmcnt(0): stage(ch)+pv(ch) landed for ALL waves
#pragma unroll
    for (int r = 0; r < 4; r++)
#pragma unroll
      for (int q = 0; q < 4; q++) pvC[r][q] = pvN[r][q];
    if (ch < 17) {
      int dnext = (ch + 1) * 256;
#pragma unroll
      for (int u = 0; u < 7; u++) {
        int row = u * 4 + wv;                   // wave-uniform
        if (row < 26)
          gload_lds16(wc + (size_t)row * DGP + dnext + 4 * l, &wlds[cur ^ 1][row * 256]);
      }
#pragma unroll
      for (int r = 0; r < 4; r++)
#pragma unroll
        for (int q = 0; q < 4; q++)
          pvN[r][q] = pr0[(size_t)r * D_G + dnext + 4 * l + q];
    }
    const float* wb = wlds[cur];
    float4 bl = *(const float4*)&wb[25 * 256 + 4 * l];
#pragma unroll
    for (int r = 0; r < 4; r++) {
      p2acc[r] += pvC[r][0]*pvC[r][0] + pvC[r][1]*pvC[r][1] + pvC[r][2]*pvC[r][2] + pvC[r][3]*pvC[r][3];
      sacc[r]  += pvC[r][0]*bl.x + pvC[r][1]*bl.y + pvC[r][2]*bl.z + pvC[r][3]*bl.w;
    }
#pragma unroll
    for (int k = 0; k < 25; k++) {
      float4 w = *(const float4*)&wb[k * 256 + 4 * l];
#pragma unroll
      for (int r = 0; r < 4; r++)
        racc[r][k] += pvC[r][0]*w.x + pvC[r][1]*w.y + pvC[r][2]*w.z + pvC[r][3]*w.w;
    }
  }
  if (l < 3) {             // d = 4608..4610 tail
    int d = 4608 + l;
#pragma unroll
    for (int r = 0; r < 4; r++) {
      float pvt = pr0[(size_t)r * D_G + d];
      p2acc[r] += pvt * pvt;
      sacc[r]  += pvt * bc[d];
#pragma unroll
      for (int k = 0; k < 25; k++) racc[r][k] += pvt * wc[(size_t)k * DGP + d];
    }
  }
#pragma unroll
  for (int r = 0; r < 4; r++) {
#pragma unroll
    for (int k = 0; k < 25; k++) {
      float v = racc[r][k];
#pragma unroll
      for (int off = 32; off > 0; off >>= 1) v += __shfl_down(v, off, 64);
      if (l == 0) ws[WS_RPAD + (size_t)(i0 + r) * KE + k] = v;
    }
    float s = sacc[r], p2 = p2acc[r];
#pragma unroll
    for (int off = 32; off > 0; off >>= 1) { s += __shfl_down(s, off, 64); p2 += __shfl_down(p2, off, 64); }
    if (l == 0) {
      ws[WS_RPAD + (size_t)(i0 + r) * KE + 25] = -0.5f * (p2 - 2.f * s);
      ws[WS_RPAD + (size_t)(i0 + r) * KE + 26] = 0.f;
      ws[WS_RPAD + (size_t)(i0 + r) * KE + 27] = 0.f;
    }
  }
}

// min over i of (alpha_i + beta_j - 2 A_i.n_j), clamped >= 0.
// LDS-free scalar-path version: the A-row is wave-uniform, so it goes through
// s_load (SMEM pipe) via sdot26's readfirstlane — zero LDS-pipe pressure,
// SGPR-sourced FMAs, no __syncthreads. Both variants (WW: z=0 skip diag,
// WP: z=1) fused into one launch via blockIdx.z -> 4 blocks/CU latency hiding.
// Bitwise-identical math to the LDS version (same FMA chain order).
__global__ __launch_bounds__(256) void k_pair2(const float* __restrict__ ppad,
                                               const float* __restrict__ rpad,
                                               const float* __restrict__ Bn,
                                               const float* __restrict__ qv,
                                               const float* __restrict__ g2v,
                                               unsigned int* __restrict__ ww2,
                                               unsigned int* __restrict__ wp2) {
  int zsel = blockIdx.z;                    // 0: WW (PPAD, q, skip diag), 1: WP (RPAD, g2)
  const float* APAD = zsel ? rpad : ppad;
  const float* beta = zsel ? g2v  : qv;
  unsigned int* outm = zsel ? wp2 : ww2;
  bool doskip = (zsel == 0);
  int t = threadIdx.x;
  int jbase = blockIdx.y * 256;
  int j0 = blockIdx.x * 512 + t;
  int j1 = j0 + 256;
  float nx0[25], nx1[25];
#pragma unroll
  for (int k = 0; k < 25; k++) { nx0[k] = Bn[j0 * 25 + k]; nx1[k] = Bn[j1 * 25 + k]; }
  float bj0 = beta[j0], bj1 = beta[j1];
  float mn0 = 3.402823466e38f, mn1 = 3.402823466e38f;
#pragma unroll 2
  for (int it = 0; it < 256; ++it) {
    int i = jbase + it;
    float a0 = sdot26(APAD, i, nx0);        // wave-uniform row -> s_load
    float a1 = sdot26(APAD, i, nx1);
    float sq0 = fmaxf(fmaf(-2.f, a0, bj0), 0.f);
    float sq1 = fmaxf(fmaf(-2.f, a1, bj1), 0.f);
    bool sk0 = doskip && (i == j0);
    bool sk1 = doskip && (i == j1);
    mn0 = sk0 ? mn0 : fminf(mn0, sq0);
    mn1 = sk1 ? mn1 : fminf(mn1, sq1);
  }
  atomicMin(&outm[j0], __float_as_uint(mn0));
  atomicMin(&outm[j1], __float_as_uint(mn1));
}

// decode phase 1: h1 = elu(W1 z + B1)
__global__ __launch_bounds__(64) void kd1(const float* __restrict__ n, const float* __restrict__ z,
                                          const float* __restrict__ ws_wt, float* __restrict__ h1t) {
  int s = blockIdx.x * 64 + threadIdx.x;
  int rb = blockIdx.y * 16;
  float nx[25];
#pragma unroll
  for (int k = 0; k < 25; k++) nx[k] = n[s * 25 + k];
  float zr[3];
#pragma unroll
  for (int d = 0; d < 3; d++) zr[d] = z[s * 3 + d];
  for (int r = 0; r < 16; r++) {
    int rr = rb + r;
    float acc = sdot26(ws_wt, 192 + rr, nx);                      // B1
#pragma unroll
    for (int d = 0; d < 3; d++)
      acc = fmaf(sdot26(ws_wt, rr * 3 + d, nx), zr[d], acc);      // W1
    h1t[rr * BATCH + s] = eluf(acc);
  }
}

// decode phase 2: h2 = elu(W2 h1 + B2)
__global__ __launch_bounds__(64) void kd2(const float* __restrict__ n,
                                          const float* __restrict__ ws_wt,
                                          const float* __restrict__ h1t, float* __restrict__ h2t) {
  int s = blockIdx.x * 64 + threadIdx.x;
  int rb = blockIdx.y * 4;
  float nx[25];
#pragma unroll
  for (int k = 0; k < 25; k++) nx[k] = n[s * 25 + k];
  float acc[4];
#pragma unroll
  for (int r = 0; r < 4; r++) acc[r] = sdot26(ws_wt, 4352 + rb + r, nx);   // B2
  for (int c = 0; c < 64; c++) {
    float h1c = h1t[c * BATCH + s];
#pragma unroll
    for (int r = 0; r < 4; r++) {
      float w = sdot26(ws_wt, 256 + (rb + r) * 64 + c, nx);                // W2
      acc[r] = fmaf(w, h1c, acc[r]);
    }
  }
#pragma unroll
  for (int r = 0; r < 4; r++) h2t[(rb + r) * BATCH + s] = eluf(acc[r]);
}

// decode phase 3: z_hat = W3 h2 + B3, recon partial
__global__ __launch_bounds__(64) void kd3(const float* __restrict__ n,
                                          const float* __restrict__ znext,
                                          const float* __restrict__ ws_wt,
                                          const float* __restrict__ h2t,
                                          float* __restrict__ out, float* __restrict__ accum) {
  int s = blockIdx.x * 64 + threadIdx.x;
  int r = blockIdx.y;
  float nx[25];
#pragma unroll
  for (int k = 0; k < 25; k++) nx[k] = n[s * 25 + k];
  float acc = sdot26(ws_wt, 4608 + r, nx);                                 // B3
  for (int c = 0; c < 64; c++)
    acc = fmaf(sdot26(ws_wt, 4416 + r * 64 + c, nx), h2t[c * BATCH + s], acc); // W3
  out[2 + s * 3 + r] = acc;
  float dz = acc - znext[s * 3 + r];
  float v = dz * dz;
#pragma unroll
  for (int off = 32; off > 0; off >>= 1) v += __shfl_down(v, off, 64);
  if (threadIdx.x == 0) atomicAdd(accum, v);
}

__global__ void k_finish(float* ws, float* __restrict__ out) {
  __shared__ float sred[256];
  int t = threadIdx.x;
  float part = 0.f;
  for (int j = t; j < BATCH; j += 256) {
    float wp2 = ws[WS_WP2 + j];
    float ww2 = ws[WS_WW2 + j];
    float wp = sqrtf(wp2 + 1e-8f);
    float ww = sqrtf(ww2 + 1e-8f);
    part += logf(wp / (ww + 1e-8f) + 1e-8f);
  }
  sred[t] = part; __syncthreads();
  for (int off = 128; off > 0; off >>= 1) { if (t < off) sred[t] += sred[t + off]; __syncthreads(); }
  if (t == 0) {
    float kl = sred[0] / (float)BATCH * (float)D_G + logf((float)BATCH / (float)(BATCH - 1));
    out[0] = ws[WS_ACC] / (float)BATCH;
    out[1] = kl;
  }
}

extern "C" void kernel_launch(void* const* d_in, const int* in_sizes, int n_in,
                              void* d_out, int out_size, void* d_ws, size_t ws_size,
                              hipStream_t stream) {
  (void)in_sizes; (void)n_in; (void)out_size; (void)ws_size;
  const float* z     = (const float*)d_in[0];
  const float* znext = (const float*)d_in[1];
  const float* n     = (const float*)d_in[2];
  const float* prior = (const float*)d_in[3];
  const float* w1W = (const float*)d_in[4];  const float* w1b = (const float*)d_in[5];
  const float* b1W = (const float*)d_in[6];  const float* b1b = (const float*)d_in[7];
  const float* w2W = (const float*)d_in[8];  const float* w2b = (const float*)d_in[9];
  const float* b2W = (const float*)d_in[10]; const float* b2b = (const float*)d_in[11];
  const float* w3W = (const float*)d_in[12]; const float* w3b = (const float*)d_in[13];
  const float* b3W = (const float*)d_in[14]; const float* b3b = (const float*)d_in[15];
  float* out = (float*)d_out;
  float* ws  = (float*)d_ws;

  k_build<<<dim3((KN * D_G + 255) / 256), dim3(256), 0, stream>>>(
      w1W, w1b, b1W, b1b, w2W, w2b, b2W, b2b, w3W, w3b, b3W, b3b, ws);
  k_M<<<dim3(26), dim3(256), 0, stream>>>(ws);
  k_persample<<<dim3(32), dim3(256), 0, stream>>>(n, ws);
  k_prior<<<dim3(512), dim3(256), 0, stream>>>(prior, ws);
  k_pair2<<<dim3(16, 32, 2), dim3(256), 0, stream>>>(
      ws + WS_PPAD, ws + WS_RPAD, n, ws + WS_Q, ws + WS_G2,
      (unsigned int*)(ws + WS_WW2), (unsigned int*)(ws + WS_WP2));
  kd1<<<dim3(128, 4), dim3(64), 0, stream>>>(n, z, ws + WS_WCATT, ws + WS_H1T);
  kd2<<<dim3(128, 16), dim3(64), 0, stream>>>(n, ws + WS_WCATT, ws + WS_H1T, ws + WS_H2T);
  kd3<<<dim3(128, 3), dim3(64), 0, stream>>>(n, znext, ws + WS_WCATT, ws + WS_H2T, out, ws + WS_ACC);
  k_finish<<<dim3(1), dim3(256), 0, stream>>>(ws, out);
}

// Round 7
// 562.007 us; speedup vs baseline: 1.0421x; 1.0421x over previous
//
#include <hip/hip_runtime.h>
#include <math.h>

#define BATCH 8192
#define D_G   4611
#define DGP   4624   // padded Wcat row stride (multiple of 16 floats for aligned float4)
#define KN    25
#define KE    28     // padded row: 25 weights, [25]=bias/alpha slot, [26..27]=0

// workspace offsets (floats)
#define WS_WCAT   0        // [25][4624]
#define WS_BCAT   115600   // [4624]  (== row 25 of WS_WCAT at stride DGP — contiguous!)
#define WS_WCATT  120224   // [4611][28]   row d = [w[0..24], bias, 0, 0]
#define WS_M      249344   // [25][25]
#define WS_C      249984   // [25]
#define WS_BB     250016   // [1]
#define WS_PPAD   250048   // [8192][28]   [25] = -q/2
#define WS_Q      479424   // [8192]
#define WS_G2     487616   // [8192]
#define WS_RPAD   495808   // [8192][28]   [25] = -T/2
#define WS_WP2    725184   // [8192] min sq bits (prior->G)
#define WS_WW2    733376   // [8192] min sq bits (G->G, i!=j)
#define WS_ACC    741568   // recon accumulator
#define WS_H1T    741600   // [64][8192]
#define WS_NT     741600   // [25][8192] n^T — ALIASES H1T: written by k_persample,
                           // consumed by k_pair (both before kd1 overwrites H1T)
#define WS_H2T    1265888  // [64][8192]

__device__ inline float eluf(float x) { return x > 0.f ? x : expm1f(x); }

// async global->LDS, 16B per lane. lds dest must be wave-uniform base (+lane*16 implicit).
__device__ __forceinline__ void gload_lds16(const float* g, float* l) {
  __builtin_amdgcn_global_load_lds((const __attribute__((address_space(1))) unsigned int*)g,
                                   (__attribute__((address_space(3))) unsigned int*)l, 16, 0, 0);
}

// dot of a wave-uniform 28-float row (25 weights + bias/alpha at [25]) with per-lane nx[25].
__device__ inline float sdot26(const float* __restrict__ WT, int rowidx, const float* nx) {
  const float* row = WT + (size_t)__builtin_amdgcn_readfirstlane(rowidx) * KE;
  float acc = row[25];
#pragma unroll
  for (int k = 0; k < 25; k++) acc = fmaf(row[k], nx[k], acc);
  return acc;
}

__global__ void k_build(const float* __restrict__ w1W, const float* __restrict__ w1b,
                        const float* __restrict__ b1W, const float* __restrict__ b1b,
                        const float* __restrict__ w2W, const float* __restrict__ w2b,
                        const float* __restrict__ b2W, const float* __restrict__ b2b,
                        const float* __restrict__ w3W, const float* __restrict__ w3b,
                        const float* __restrict__ b3W, const float* __restrict__ b3b,
                        float* ws) {
  int idx = blockIdx.x * 256 + threadIdx.x;
  // folded k_init (grid covers 2*BATCH+1 easily)
  unsigned int* u = (unsigned int*)ws;
  if (idx < BATCH)            u[WS_WP2 + idx] = 0x7F7FFFFFu;
  else if (idx < 2 * BATCH)   u[WS_WW2 + (idx - BATCH)] = 0x7F7FFFFFu;
  else if (idx == 2 * BATCH)  ws[WS_ACC] = 0.f;
  if (idx >= KN * D_G) return;
  int k = idx / D_G;
  int d = idx - k * D_G;
  float wv, bv;
  if (d < 192)       { int c = d;        wv = w1W[k*192  + c]; bv = w1b[c]; }
  else if (d < 256)  { int c = d - 192;  wv = b1W[k*64   + c]; bv = b1b[c]; }
  else if (d < 4352) { int c = d - 256;  wv = w2W[k*4096 + c]; bv = w2b[c]; }
  else if (d < 4416) { int c = d - 4352; wv = b2W[k*64   + c]; bv = b2b[c]; }
  else if (d < 4608) { int c = d - 4416; wv = w3W[k*192  + c]; bv = w3b[c]; }
  else               { int c = d - 4608; wv = b3W[k*3    + c]; bv = b3b[c]; }
  ws[WS_WCAT  + k * DGP + d] = wv;
  ws[WS_WCATT + d * KE  + k] = wv;
  if (k == 0) {
    ws[WS_BCAT + d] = bv;
    ws[WS_WCATT + d * KE + 25] = bv;
    ws[WS_WCATT + d * KE + 26] = 0.f;
    ws[WS_WCATT + d * KE + 27] = 0.f;
  }
}

// M = Wcat Wcat^T (25x25), c = Wcat bcat, bb = |bcat|^2 — shfl-based reduction
__global__ __launch_bounds__(256) void k_M(float* ws) {
  const float* Wc = ws + WS_WCAT;
  const float* bc = ws + WS_BCAT;
  __shared__ float part[4][26];
  int a = blockIdx.x, t = threadIdx.x;
  int wv = t >> 6, l = t & 63;
  if (a < 25) {
    float acc[26];
#pragma unroll
    for (int v = 0; v < 26; v++) acc[v] = 0.f;
    for (int d = t; d < D_G; d += 256) {
      float va = Wc[a * DGP + d];
#pragma unroll
      for (int b = 0; b < 25; b++) acc[b] += va * Wc[b * DGP + d];
      acc[25] += va * bc[d];
    }
#pragma unroll
    for (int v = 0; v < 26; v++) {
      float x = acc[v];
#pragma unroll
      for (int off = 32; off > 0; off >>= 1) x += __shfl_down(x, off, 64);
      if (l == 0) part[wv][v] = x;
    }
    __syncthreads();
    if (t < 26) {
      float s = part[0][t] + part[1][t] + part[2][t] + part[3][t];
      if (t < 25) ws[WS_M + a * 25 + t] = s; else ws[WS_C + a] = s;
    }
  } else {
    float acc = 0.f;
    for (int d = t; d < D_G; d += 256) { float b = bc[d]; acc += b * b; }
#pragma unroll
    for (int off = 32; off > 0; off >>= 1) acc += __shfl_down(acc, off, 64);
    if (l == 0) part[wv][0] = acc;
    __syncthreads();
    if (t == 0) ws[WS_BB] = part[0][0] + part[1][0] + part[2][0] + part[3][0];
  }
}

// PPAD rows, q, g2 — also writes n^T (coalesced) for k_pair
__global__ void k_persample(const float* __restrict__ n, float* ws) {
  int j = blockIdx.x * 256 + threadIdx.x;
  if (j >= BATCH) return;
  const float* M  = ws + WS_M;
  const float* cv = ws + WS_C;
  float nr[25];
#pragma unroll
  for (int k = 0; k < 25; k++) nr[k] = n[j * 25 + k];
#pragma unroll
  for (int k = 0; k < 25; k++) ws[WS_NT + k * BATCH + j] = nr[k];   // n^T, coalesced
  float q = 0.f;
  for (int k2 = 0; k2 < 25; k2++) {
    float p = 0.f;
#pragma unroll
    for (int k1 = 0; k1 < 25; k1++) p += nr[k1] * M[k1 * 25 + k2];
    ws[WS_PPAD + j * KE + k2] = p;
    q += p * nr[k2];
  }
  float nc = 0.f;
#pragma unroll
  for (int k = 0; k < 25; k++) nc += nr[k] * cv[k];
  ws[WS_PPAD + j * KE + 25] = -0.5f * q;
  ws[WS_PPAD + j * KE + 26] = 0.f;
  ws[WS_PPAD + j * KE + 27] = 0.f;
  ws[WS_Q  + j] = q;
  ws[WS_G2 + j] = q + 2.f * nc + ws[WS_BB];
}

// RPAD rows: r_i = prior_i @ Wcat^T, [25] = -0.5*(|p_i|^2 - 2 p_i.bcat)
// R1-proven pipeline (93 µs, no spills): double-buffered LDS staged by async
// global_load_lds, prior values register-double-buffered (2-deep only — 3-deep
// spills, see R4), one __syncthreads per chunk.
// SPILL TRIPWIRE: WRITE_SIZE must stay ~0.9 MB; any MB-scale growth = scratch.
__global__ __launch_bounds__(256, 2) void k_prior(const float* __restrict__ prior, float* ws) {
  __shared__ float wlds[2][26 * 256 + 512];   // 28 rows x 256 floats per buffer (rows 26/27 unused pad)
  const float* wc = ws + WS_WCAT;   // rows 0..24 Wcat, row 25 = bcat (stride DGP)
  const float* bc = ws + WS_BCAT;
  int t = threadIdx.x;
  int wv = t >> 6, l = t & 63;
  int i0 = (blockIdx.x * 4 + wv) * 4;  // 4 rows per wave
  const float* pr0 = prior + (size_t)i0 * D_G;

  float racc[4][25];
  float sacc[4], p2acc[4];
#pragma unroll
  for (int r = 0; r < 4; r++) {
    sacc[r] = 0.f; p2acc[r] = 0.f;
#pragma unroll
    for (int k = 0; k < 25; k++) racc[r][k] = 0.f;
  }

  float pvC[4][4], pvN[4][4];

  // prologue: stage chunk 0 (async) + issue prior loads for chunk 0
#pragma unroll
  for (int u = 0; u < 7; u++) {
    int row = u * 4 + wv;                       // wave-uniform
    if (row < 26)
      gload_lds16(wc + (size_t)row * DGP + 4 * l, &wlds[0][row * 256]);
  }
#pragma unroll
  for (int r = 0; r < 4; r++)
#pragma unroll
    for (int q = 0; q < 4; q++)
      pvN[r][q] = pr0[(size_t)r * D_G + 4 * l + q];

  for (int ch = 0; ch < 18; ++ch) {
    int cur = ch & 1;
    __syncthreads();   // implicit vmcnt(0): stage(ch)+pv(ch) landed for ALL waves
#pragma unroll
    for (int r = 0; r < 4; r++)
#pragma unroll
      for (int q = 0; q < 4; q++) pvC[r][q] = pvN[r][q];
    if (ch < 17) {
      int dnext = (ch + 1) * 256;
#pragma unroll
      for (int u = 0; u < 7; u++) {
        int row = u * 4 + wv;                   // wave-uniform
        if (row < 26)
          gload_lds16(wc + (size_t)row * DGP + dnext + 4 * l, &wlds[cur ^ 1][row * 256]);
      }
#pragma unroll
      for (int r = 0; r < 4; r++)
#pragma unroll
        for (int q = 0; q < 4; q++)
          pvN[r][q] = pr0[(size_t)r * D_G + dnext + 4 * l + q];
    }
    const float* wb = wlds[cur];
    float4 bl = *(const float4*)&wb[25 * 256 + 4 * l];
#pragma unroll
    for (int r = 0; r < 4; r++) {
      p2acc[r] += pvC[r][0]*pvC[r][0] + pvC[r][1]*pvC[r][1] + pvC[r][2]*pvC[r][2] + pvC[r][3]*pvC[r][3];
      sacc[r]  += pvC[r][0]*bl.x + pvC[r][1]*bl.y + pvC[r][2]*bl.z + pvC[r][3]*bl.w;
    }
#pragma unroll
    for (int k = 0; k < 25; k++) {
      float4 w = *(const float4*)&wb[k * 256 + 4 * l];
#pragma unroll
      for (int r = 0; r < 4; r++)
        racc[r][k] += pvC[r][0]*w.x + pvC[r][1]*w.y + pvC[r][2]*w.z + pvC[r][3]*w.w;
    }
  }
  if (l < 3) {             // d = 4608..4610 tail
    int d = 4608 + l;
#pragma unroll
    for (int r = 0; r < 4; r++) {
      float pvt = pr0[(size_t)r * D_G + d];
      p2acc[r] += pvt * pvt;
      sacc[r]  += pvt * bc[d];
#pragma unroll
      for (int k = 0; k < 25; k++) racc[r][k] += pvt * wc[(size_t)k * DGP + d];
    }
  }
#pragma unroll
  for (int r = 0; r < 4; r++) {
#pragma unroll
    for (int k = 0; k < 25; k++) {
      float v = racc[r][k];
#pragma unroll
      for (int off = 32; off > 0; off >>= 1) v += __shfl_down(v, off, 64);
      if (l == 0) ws[WS_RPAD + (size_t)(i0 + r) * KE + k] = v;
    }
    float s = sacc[r], p2 = p2acc[r];
#pragma unroll
    for (int off = 32; off > 0; off >>= 1) { s += __shfl_down(s, off, 64); p2 += __shfl_down(p2, off, 64); }
    if (l == 0) {
      ws[WS_RPAD + (size_t)(i0 + r) * KE + 25] = -0.5f * (p2 - 2.f * s);
      ws[WS_RPAD + (size_t)(i0 + r) * KE + 26] = 0.f;
      ws[WS_RPAD + (size_t)(i0 + r) * KE + 27] = 0.f;
    }
  }
}

// min over i of (alpha_i + beta_j - 2 A_i.n_j), clamped >= 0.
// JT=4: each thread owns 4 j's — the 7 wave-uniform LDS b128 broadcasts per
// i-row now feed 104 FMAs (VALU-bound) instead of 52. 128-row i-slices keep
// the grid at 512 blocks (2 blocks/CU). nx loads are coalesced via n^T.
// Per-j FMA chain order identical to before -> bitwise-identical output.
// SPILL TRIPWIRE: WRITE_SIZE per dispatch should stay ~1 MB.
template <int SKIP>
__global__ __launch_bounds__(256) void k_pair(const float* __restrict__ APAD,
                                              const float* __restrict__ nT,
                                              const float* __restrict__ beta,
                                              unsigned int* __restrict__ outm) {
  __shared__ float rows[128 * KE] __attribute__((aligned(16)));  // 14336 B
  int t = threadIdx.x;
  int ibase = blockIdx.y * 128;
  {
    const float4* src = (const float4*)(APAD + (size_t)ibase * KE);
    float4* dst = (float4*)rows;
#pragma unroll
    for (int u = 0; u < 4; u++) {
      int idx = t + 256 * u;
      if (idx < 896) dst[idx] = src[idx];
    }
  }
  int j0 = blockIdx.x * 1024 + t;       // j0, +256, +512, +768
  float nx0[25], nx1[25], nx2[25], nx3[25];
#pragma unroll
  for (int k = 0; k < 25; k++) {
    nx0[k] = nT[k * BATCH + j0];
    nx1[k] = nT[k * BATCH + j0 + 256];
    nx2[k] = nT[k * BATCH + j0 + 512];
    nx3[k] = nT[k * BATCH + j0 + 768];
  }
  float bj0 = beta[j0], bj1 = beta[j0 + 256], bj2 = beta[j0 + 512], bj3 = beta[j0 + 768];
  float mn0 = 3.402823466e38f, mn1 = mn0, mn2 = mn0, mn3 = mn0;
  __syncthreads();
  for (int it = 0; it < 128; ++it) {
    const float4* rv = (const float4*)(rows + it * KE);   // wave-uniform, 16B-aligned
    float rw[28];
#pragma unroll
    for (int u = 0; u < 7; u++) *(float4*)&rw[4 * u] = rv[u];
    float a0 = rw[25], a1 = rw[25], a2 = rw[25], a3 = rw[25];
#pragma unroll
    for (int k = 0; k < 25; k++) {
      a0 = fmaf(rw[k], nx0[k], a0);
      a1 = fmaf(rw[k], nx1[k], a1);
      a2 = fmaf(rw[k], nx2[k], a2);
      a3 = fmaf(rw[k], nx3[k], a3);
    }
    float sq0 = fmaxf(fmaf(-2.f, a0, bj0), 0.f);
    float sq1 = fmaxf(fmaf(-2.f, a1, bj1), 0.f);
    float sq2 = fmaxf(fmaf(-2.f, a2, bj2), 0.f);
    float sq3 = fmaxf(fmaf(-2.f, a3, bj3), 0.f);
    int i = ibase + it;
    mn0 = (SKIP && i == j0)       ? mn0 : fminf(mn0, sq0);
    mn1 = (SKIP && i == j0 + 256) ? mn1 : fminf(mn1, sq1);
    mn2 = (SKIP && i == j0 + 512) ? mn2 : fminf(mn2, sq2);
    mn3 = (SKIP && i == j0 + 768) ? mn3 : fminf(mn3, sq3);
  }
  atomicMin(&outm[j0],       __float_as_uint(mn0));
  atomicMin(&outm[j0 + 256], __float_as_uint(mn1));
  atomicMin(&outm[j0 + 512], __float_as_uint(mn2));
  atomicMin(&outm[j0 + 768], __float_as_uint(mn3));
}

// decode phase 1: h1 = elu(W1 z + B1)
__global__ __launch_bounds__(64) void kd1(const float* __restrict__ n, const float* __restrict__ z,
                                          const float* __restrict__ ws_wt, float* __restrict__ h1t) {
  int s = blockIdx.x * 64 + threadIdx.x;
  int rb = blockIdx.y * 16;
  float nx[25];
#pragma unroll
  for (int k = 0; k < 25; k++) nx[k] = n[s * 25 + k];
  float zr[3];
#pragma unroll
  for (int d = 0; d < 3; d++) zr[d] = z[s * 3 + d];
  for (int r = 0; r < 16; r++) {
    int rr = rb + r;
    float acc = sdot26(ws_wt, 192 + rr, nx);                      // B1
#pragma unroll
    for (int d = 0; d < 3; d++)
      acc = fmaf(sdot26(ws_wt, rr * 3 + d, nx), zr[d], acc);      // W1
    h1t[rr * BATCH + s] = eluf(acc);
  }
}

// decode phase 2: h2 = elu(W2 h1 + B2)
__global__ __launch_bounds__(64) void kd2(const float* __restrict__ n,
                                          const float* __restrict__ ws_wt,
                                          const float* __restrict__ h1t, float* __restrict__ h2t) {
  int s = blockIdx.x * 64 + threadIdx.x;
  int rb = blockIdx.y * 4;
  float nx[25];
#pragma unroll
  for (int k = 0; k < 25; k++) nx[k] = n[s * 25 + k];
  float acc[4];
#pragma unroll
  for (int r = 0; r < 4; r++) acc[r] = sdot26(ws_wt, 4352 + rb + r, nx);   // B2
  for (int c = 0; c < 64; c++) {
    float h1c = h1t[c * BATCH + s];
#pragma unroll
    for (int r = 0; r < 4; r++) {
      float w = sdot26(ws_wt, 256 + (rb + r) * 64 + c, nx);                // W2
      acc[r] = fmaf(w, h1c, acc[r]);
    }
  }
#pragma unroll
  for (int r = 0; r < 4; r++) h2t[(rb + r) * BATCH + s] = eluf(acc[r]);
}

// decode phase 3: z_hat = W3 h2 + B3, recon partial
__global__ __launch_bounds__(64) void kd3(const float* __restrict__ n,
                                          const float* __restrict__ znext,
                                          const float* __restrict__ ws_wt,
                                          const float* __restrict__ h2t,
                                          float* __restrict__ out, float* __restrict__ accum) {
  int s = blockIdx.x * 64 + threadIdx.x;
  int r = blockIdx.y;
  float nx[25];
#pragma unroll
  for (int k = 0; k < 25; k++) nx[k] = n[s * 25 + k];
  float acc = sdot26(ws_wt, 4608 + r, nx);                                 // B3
  for (int c = 0; c < 64; c++)
    acc = fmaf(sdot26(ws_wt, 4416 + r * 64 + c, nx), h2t[c * BATCH + s], acc); // W3
  out[2 + s * 3 + r] = acc;
  float dz = acc - znext[s * 3 + r];
  float v = dz * dz;
#pragma unroll
  for (int off = 32; off > 0; off >>= 1) v += __shfl_down(v, off, 64);
  if (threadIdx.x == 0) atomicAdd(accum, v);
}

__global__ void k_finish(float* ws, float* __restrict__ out) {
  __shared__ float sred[256];
  int t = threadIdx.x;
  float part = 0.f;
  for (int j = t; j < BATCH; j += 256) {
    float wp2 = ws[WS_WP2 + j];
    float ww2 = ws[WS_WW2 + j];
    float wp = sqrtf(wp2 + 1e-8f);
    float ww = sqrtf(ww2 + 1e-8f);
    part += logf(wp / (ww + 1e-8f) + 1e-8f);
  }
  sred[t] = part; __syncthreads();
  for (int off = 128; off > 0; off >>= 1) { if (t < off) sred[t] += sred[t + off]; __syncthreads(); }
  if (t == 0) {
    float kl = sred[0] / (float)BATCH * (float)D_G + logf((float)BATCH / (float)(BATCH - 1));
    out[0] = ws[WS_ACC] / (float)BATCH;
    out[1] = kl;
  }
}

extern "C" void kernel_launch(void* const* d_in, const int* in_sizes, int n_in,
                              void* d_out, int out_size, void* d_ws, size_t ws_size,
                              hipStream_t stream) {
  (void)in_sizes; (void)n_in; (void)out_size; (void)ws_size;
  const float* z     = (const float*)d_in[0];
  const float* znext = (const float*)d_in[1];
  const float* n     = (const float*)d_in[2];
  const float* prior = (const float*)d_in[3];
  const float* w1W = (const float*)d_in[4];  const float* w1b = (const float*)d_in[5];
  const float* b1W = (const float*)d_in[6];  const float* b1b = (const float*)d_in[7];
  const float* w2W = (const float*)d_in[8];  const float* w2b = (const float*)d_in[9];
  const float* b2W = (const float*)d_in[10]; const float* b2b = (const float*)d_in[11];
  const float* w3W = (const float*)d_in[12]; const float* w3b = (const float*)d_in[13];
  const float* b3W = (const float*)d_in[14]; const float* b3b = (const float*)d_in[15];
  float* out = (float*)d_out;
  float* ws  = (float*)d_ws;

  k_build<<<dim3((KN * D_G + 255) / 256), dim3(256), 0, stream>>>(
      w1W, w1b, b1W, b1b, w2W, w2b, b2W, b2b, w3W, w3b, b3W, b3b, ws);
  k_M<<<dim3(26), dim3(256), 0, stream>>>(ws);
  k_persample<<<dim3(32), dim3(256), 0, stream>>>(n, ws);
  k_prior<<<dim3(512), dim3(256), 0, stream>>>(prior, ws);
  k_pair<1><<<dim3(8, 64), dim3(256), 0, stream>>>(ws + WS_PPAD, ws + WS_NT, ws + WS_Q,
                                                   (unsigned int*)(ws + WS_WW2));
  k_pair<0><<<dim3(8, 64), dim3(256), 0, stream>>>(ws + WS_RPAD, ws + WS_NT, ws + WS_G2,
                                                   (unsigned int*)(ws + WS_WP2));
  kd1<<<dim3(128, 4), dim3(64), 0, stream>>>(n, z, ws + WS_WCATT, ws + WS_H1T);
  kd2<<<dim3(128, 16), dim3(64), 0, stream>>>(n, ws + WS_WCATT, ws + WS_H1T, ws + WS_H2T);
  kd3<<<dim3(128, 3), dim3(64), 0, stream>>>(n, znext, ws + WS_WCATT, ws + WS_H2T, out, ws + WS_ACC);
  k_finish<<<dim3(1), dim3(256), 0, stream>>>(ws, out);
}

// Round 8
// 531.376 us; speedup vs baseline: 1.1022x; 1.0576x over previous
//
#include <hip/hip_runtime.h>
#include <math.h>

#define BATCH 8192
#define D_G   4611
#define DGP   4624   // padded Wcat row stride (multiple of 16 floats for aligned float4)
#define KN    25
#define KE    28     // padded row: 25 weights, [25]=bias/alpha slot, [26..27]=0

// workspace offsets (floats)
#define WS_WCAT   0        // [25][4624]
#define WS_BCAT   115600   // [4624]  (== row 25 of WS_WCAT at stride DGP — contiguous!)
#define WS_WCATT  120224   // [4611][28]   row d = [w[0..24], bias, 0, 0]
#define WS_M      249344   // [25][25]
#define WS_C      249984   // [25]
#define WS_BB     250016   // [1]
#define WS_PPAD   250048   // [8192][28]   [25] = -q/2
#define WS_Q      479424   // [8192]
#define WS_G2     487616   // [8192]
#define WS_RPAD   495808   // [8192][28]   [25] = -T/2
#define WS_WP2    725184   // [8192] min sq bits (prior->G)
#define WS_WW2    733376   // [8192] min sq bits (G->G, i!=j)
#define WS_ACC    741568   // recon accumulator
#define WS_H1T    741600   // [64][8192]
#define WS_NT     741600   // [25][8192] n^T — ALIASES H1T: written by k_persample,
                           // consumed by k_pair (both before kd1 overwrites H1T)
#define WS_H2T    1265888  // [64][8192]

__device__ inline float eluf(float x) { return x > 0.f ? x : expm1f(x); }

// async global->LDS, 16B per lane. lds dest must be wave-uniform base (+lane*16 implicit).
__device__ __forceinline__ void gload_lds16(const float* g, float* l) {
  __builtin_amdgcn_global_load_lds((const __attribute__((address_space(1))) unsigned int*)g,
                                   (__attribute__((address_space(3))) unsigned int*)l, 16, 0, 0);
}

// 16B load from a 4-byte-aligned address (D_G odd -> prior rows alternate 16B
// alignment; memcpy lets the compiler emit global_load_dwordx4 at align 4).
__device__ __forceinline__ void load4u(float* dst, const float* src) {
  __builtin_memcpy(dst, src, 16);
}

// dot of a wave-uniform 28-float row (25 weights + bias/alpha at [25]) with per-lane nx[25].
__device__ inline float sdot26(const float* __restrict__ WT, int rowidx, const float* nx) {
  const float* row = WT + (size_t)__builtin_amdgcn_readfirstlane(rowidx) * KE;
  float acc = row[25];
#pragma unroll
  for (int k = 0; k < 25; k++) acc = fmaf(row[k], nx[k], acc);
  return acc;
}

__global__ void k_build(const float* __restrict__ w1W, const float* __restrict__ w1b,
                        const float* __restrict__ b1W, const float* __restrict__ b1b,
                        const float* __restrict__ w2W, const float* __restrict__ w2b,
                        const float* __restrict__ b2W, const float* __restrict__ b2b,
                        const float* __restrict__ w3W, const float* __restrict__ w3b,
                        const float* __restrict__ b3W, const float* __restrict__ b3b,
                        float* ws) {
  int idx = blockIdx.x * 256 + threadIdx.x;
  // folded k_init (grid covers 2*BATCH+1 easily)
  unsigned int* u = (unsigned int*)ws;
  if (idx < BATCH)            u[WS_WP2 + idx] = 0x7F7FFFFFu;
  else if (idx < 2 * BATCH)   u[WS_WW2 + (idx - BATCH)] = 0x7F7FFFFFu;
  else if (idx == 2 * BATCH)  ws[WS_ACC] = 0.f;
  if (idx >= KN * D_G) return;
  int k = idx / D_G;
  int d = idx - k * D_G;
  float wv, bv;
  if (d < 192)       { int c = d;        wv = w1W[k*192  + c]; bv = w1b[c]; }
  else if (d < 256)  { int c = d - 192;  wv = b1W[k*64   + c]; bv = b1b[c]; }
  else if (d < 4352) { int c = d - 256;  wv = w2W[k*4096 + c]; bv = w2b[c]; }
  else if (d < 4416) { int c = d - 4352; wv = b2W[k*64   + c]; bv = b2b[c]; }
  else if (d < 4608) { int c = d - 4416; wv = w3W[k*192  + c]; bv = w3b[c]; }
  else               { int c = d - 4608; wv = b3W[k*3    + c]; bv = b3b[c]; }
  ws[WS_WCAT  + k * DGP + d] = wv;
  ws[WS_WCATT + d * KE  + k] = wv;
  if (k == 0) {
    ws[WS_BCAT + d] = bv;
    ws[WS_WCATT + d * KE + 25] = bv;
    ws[WS_WCATT + d * KE + 26] = 0.f;
    ws[WS_WCATT + d * KE + 27] = 0.f;
  }
}

// M = Wcat Wcat^T (25x25), c = Wcat bcat, bb = |bcat|^2 — shfl-based reduction
__global__ __launch_bounds__(256) void k_M(float* ws) {
  const float* Wc = ws + WS_WCAT;
  const float* bc = ws + WS_BCAT;
  __shared__ float part[4][26];
  int a = blockIdx.x, t = threadIdx.x;
  int wv = t >> 6, l = t & 63;
  if (a < 25) {
    float acc[26];
#pragma unroll
    for (int v = 0; v < 26; v++) acc[v] = 0.f;
    for (int d = t; d < D_G; d += 256) {
      float va = Wc[a * DGP + d];
#pragma unroll
      for (int b = 0; b < 25; b++) acc[b] += va * Wc[b * DGP + d];
      acc[25] += va * bc[d];
    }
#pragma unroll
    for (int v = 0; v < 26; v++) {
      float x = acc[v];
#pragma unroll
      for (int off = 32; off > 0; off >>= 1) x += __shfl_down(x, off, 64);
      if (l == 0) part[wv][v] = x;
    }
    __syncthreads();
    if (t < 26) {
      float s = part[0][t] + part[1][t] + part[2][t] + part[3][t];
      if (t < 25) ws[WS_M + a * 25 + t] = s; else ws[WS_C + a] = s;
    }
  } else {
    float acc = 0.f;
    for (int d = t; d < D_G; d += 256) { float b = bc[d]; acc += b * b; }
#pragma unroll
    for (int off = 32; off > 0; off >>= 1) acc += __shfl_down(acc, off, 64);
    if (l == 0) part[wv][0] = acc;
    __syncthreads();
    if (t == 0) ws[WS_BB] = part[0][0] + part[1][0] + part[2][0] + part[3][0];
  }
}

// PPAD rows, q, g2 — also writes n^T (coalesced) for k_pair
__global__ void k_persample(const float* __restrict__ n, float* ws) {
  int j = blockIdx.x * 256 + threadIdx.x;
  if (j >= BATCH) return;
  const float* M  = ws + WS_M;
  const float* cv = ws + WS_C;
  float nr[25];
#pragma unroll
  for (int k = 0; k < 25; k++) nr[k] = n[j * 25 + k];
#pragma unroll
  for (int k = 0; k < 25; k++) ws[WS_NT + k * BATCH + j] = nr[k];   // n^T, coalesced
  float q = 0.f;
  for (int k2 = 0; k2 < 25; k2++) {
    float p = 0.f;
#pragma unroll
    for (int k1 = 0; k1 < 25; k1++) p += nr[k1] * M[k1 * 25 + k2];
    ws[WS_PPAD + j * KE + k2] = p;
    q += p * nr[k2];
  }
  float nc = 0.f;
#pragma unroll
  for (int k = 0; k < 25; k++) nc += nr[k] * cv[k];
  ws[WS_PPAD + j * KE + 25] = -0.5f * q;
  ws[WS_PPAD + j * KE + 26] = 0.f;
  ws[WS_PPAD + j * KE + 27] = 0.f;
  ws[WS_Q  + j] = q;
  ws[WS_G2 + j] = q + 2.f * nc + ws[WS_BB];
}

// RPAD rows: r_i = prior_i @ Wcat^T, [25] = -0.5*(|p_i|^2 - 2 p_i.bcat)
// R1-proven pipeline, occupancy-tuned: LDS pad removed -> exactly 53,248 B
// -> 3 blocks/CU (was 2 at 57,344). pv loads merged to dwordx4 via align-4
// memcpy. Same math, same order -> bitwise-identical.
// SPILL TRIPWIRE: WRITE_SIZE must stay ~0.9 MB; any MB-scale growth = scratch.
__global__ __launch_bounds__(256, 2) void k_prior(const float* __restrict__ prior, float* ws) {
  __shared__ float wlds[2][26 * 256];         // 53,248 B total -> 3 blocks/CU
  const float* wc = ws + WS_WCAT;   // rows 0..24 Wcat, row 25 = bcat (stride DGP)
  const float* bc = ws + WS_BCAT;
  int t = threadIdx.x;
  int wv = t >> 6, l = t & 63;
  int i0 = (blockIdx.x * 4 + wv) * 4;  // 4 rows per wave
  const float* pr0 = prior + (size_t)i0 * D_G;

  float racc[4][25];
  float sacc[4], p2acc[4];
#pragma unroll
  for (int r = 0; r < 4; r++) {
    sacc[r] = 0.f; p2acc[r] = 0.f;
#pragma unroll
    for (int k = 0; k < 25; k++) racc[r][k] = 0.f;
  }

  float pvC[4][4], pvN[4][4];

  // prologue: stage chunk 0 (async) + issue prior loads for chunk 0
#pragma unroll
  for (int u = 0; u < 7; u++) {
    int row = u * 4 + wv;                       // wave-uniform
    if (row < 26)
      gload_lds16(wc + (size_t)row * DGP + 4 * l, &wlds[0][row * 256]);
  }
#pragma unroll
  for (int r = 0; r < 4; r++)
    load4u(pvN[r], pr0 + (size_t)r * D_G + 4 * l);

  for (int ch = 0; ch < 18; ++ch) {
    int cur = ch & 1;
    __syncthreads();   // implicit vmcnt(0): stage(ch)+pv(ch) landed for ALL waves
#pragma unroll
    for (int r = 0; r < 4; r++)
#pragma unroll
      for (int q = 0; q < 4; q++) pvC[r][q] = pvN[r][q];
    if (ch < 17) {
      int dnext = (ch + 1) * 256;
#pragma unroll
      for (int u = 0; u < 7; u++) {
        int row = u * 4 + wv;                   // wave-uniform
        if (row < 26)
          gload_lds16(wc + (size_t)row * DGP + dnext + 4 * l, &wlds[cur ^ 1][row * 256]);
      }
#pragma unroll
      for (int r = 0; r < 4; r++)
        load4u(pvN[r], pr0 + (size_t)r * D_G + dnext + 4 * l);
    }
    const float* wb = wlds[cur];
    float4 bl = *(const float4*)&wb[25 * 256 + 4 * l];
#pragma unroll
    for (int r = 0; r < 4; r++) {
      p2acc[r] += pvC[r][0]*pvC[r][0] + pvC[r][1]*pvC[r][1] + pvC[r][2]*pvC[r][2] + pvC[r][3]*pvC[r][3];
      sacc[r]  += pvC[r][0]*bl.x + pvC[r][1]*bl.y + pvC[r][2]*bl.z + pvC[r][3]*bl.w;
    }
#pragma unroll
    for (int k = 0; k < 25; k++) {
      float4 w = *(const float4*)&wb[k * 256 + 4 * l];
#pragma unroll
      for (int r = 0; r < 4; r++)
        racc[r][k] += pvC[r][0]*w.x + pvC[r][1]*w.y + pvC[r][2]*w.z + pvC[r][3]*w.w;
    }
  }
  if (l < 3) {             // d = 4608..4610 tail
    int d = 4608 + l;
#pragma unroll
    for (int r = 0; r < 4; r++) {
      float pvt = pr0[(size_t)r * D_G + d];
      p2acc[r] += pvt * pvt;
      sacc[r]  += pvt * bc[d];
#pragma unroll
      for (int k = 0; k < 25; k++) racc[r][k] += pvt * wc[(size_t)k * DGP + d];
    }
  }
#pragma unroll
  for (int r = 0; r < 4; r++) {
#pragma unroll
    for (int k = 0; k < 25; k++) {
      float v = racc[r][k];
#pragma unroll
      for (int off = 32; off > 0; off >>= 1) v += __shfl_down(v, off, 64);
      if (l == 0) ws[WS_RPAD + (size_t)(i0 + r) * KE + k] = v;
    }
    float s = sacc[r], p2 = p2acc[r];
#pragma unroll
    for (int off = 32; off > 0; off >>= 1) { s += __shfl_down(s, off, 64); p2 += __shfl_down(p2, off, 64); }
    if (l == 0) {
      ws[WS_RPAD + (size_t)(i0 + r) * KE + 25] = -0.5f * (p2 - 2.f * s);
      ws[WS_RPAD + (size_t)(i0 + r) * KE + 26] = 0.f;
      ws[WS_RPAD + (size_t)(i0 + r) * KE + 27] = 0.f;
    }
  }
}

// min over i of (alpha_i + beta_j - 2 A_i.n_j), clamped >= 0.
// JT=4, both variants fused via blockIdx.z (z=0: WW/PPAD/skip-diag, z=1: WP/RPAD).
// min is order-independent -> bitwise-identical to separate launches.
__global__ __launch_bounds__(256) void k_pair(const float* __restrict__ ppad,
                                              const float* __restrict__ rpad,
                                              const float* __restrict__ nT,
                                              const float* __restrict__ qv,
                                              const float* __restrict__ g2v,
                                              unsigned int* __restrict__ ww2,
                                              unsigned int* __restrict__ wp2) {
  int zsel = blockIdx.z;
  const float* APAD = zsel ? rpad : ppad;
  const float* beta = zsel ? g2v  : qv;
  unsigned int* outm = zsel ? wp2 : ww2;
  __shared__ float rows[128 * KE] __attribute__((aligned(16)));  // 14336 B
  int t = threadIdx.x;
  int ibase = blockIdx.y * 128;
  {
    const float4* src = (const float4*)(APAD + (size_t)ibase * KE);
    float4* dst = (float4*)rows;
#pragma unroll
    for (int u = 0; u < 4; u++) {
      int idx = t + 256 * u;
      if (idx < 896) dst[idx] = src[idx];
    }
  }
  int j0 = blockIdx.x * 1024 + t;       // j0, +256, +512, +768
  float nx0[25], nx1[25], nx2[25], nx3[25];
#pragma unroll
  for (int k = 0; k < 25; k++) {
    nx0[k] = nT[k * BATCH + j0];
    nx1[k] = nT[k * BATCH + j0 + 256];
    nx2[k] = nT[k * BATCH + j0 + 512];
    nx3[k] = nT[k * BATCH + j0 + 768];
  }
  float bj0 = beta[j0], bj1 = beta[j0 + 256], bj2 = beta[j0 + 512], bj3 = beta[j0 + 768];
  float mn0 = 3.402823466e38f, mn1 = mn0, mn2 = mn0, mn3 = mn0;
  __syncthreads();
  for (int it = 0; it < 128; ++it) {
    const float4* rv = (const float4*)(rows + it * KE);   // wave-uniform, 16B-aligned
    float rw[28];
#pragma unroll
    for (int u = 0; u < 7; u++) *(float4*)&rw[4 * u] = rv[u];
    float a0 = rw[25], a1 = rw[25], a2 = rw[25], a3 = rw[25];
#pragma unroll
    for (int k = 0; k < 25; k++) {
      a0 = fmaf(rw[k], nx0[k], a0);
      a1 = fmaf(rw[k], nx1[k], a1);
      a2 = fmaf(rw[k], nx2[k], a2);
      a3 = fmaf(rw[k], nx3[k], a3);
    }
    float sq0 = fmaxf(fmaf(-2.f, a0, bj0), 0.f);
    float sq1 = fmaxf(fmaf(-2.f, a1, bj1), 0.f);
    float sq2 = fmaxf(fmaf(-2.f, a2, bj2), 0.f);
    float sq3 = fmaxf(fmaf(-2.f, a3, bj3), 0.f);
    int i = ibase + it;
    bool skip = (zsel == 0);
    mn0 = (skip && i == j0)       ? mn0 : fminf(mn0, sq0);
    mn1 = (skip && i == j0 + 256) ? mn1 : fminf(mn1, sq1);
    mn2 = (skip && i == j0 + 512) ? mn2 : fminf(mn2, sq2);
    mn3 = (skip && i == j0 + 768) ? mn3 : fminf(mn3, sq3);
  }
  atomicMin(&outm[j0],       __float_as_uint(mn0));
  atomicMin(&outm[j0 + 256], __float_as_uint(mn1));
  atomicMin(&outm[j0 + 512], __float_as_uint(mn2));
  atomicMin(&outm[j0 + 768], __float_as_uint(mn3));
}

// decode phase 1: h1 = elu(W1 z + B1)
__global__ __launch_bounds__(64) void kd1(const float* __restrict__ n, const float* __restrict__ z,
                                          const float* __restrict__ ws_wt, float* __restrict__ h1t) {
  int s = blockIdx.x * 64 + threadIdx.x;
  int rb = blockIdx.y * 16;
  float nx[25];
#pragma unroll
  for (int k = 0; k < 25; k++) nx[k] = n[s * 25 + k];
  float zr[3];
#pragma unroll
  for (int d = 0; d < 3; d++) zr[d] = z[s * 3 + d];
  for (int r = 0; r < 16; r++) {
    int rr = rb + r;
    float acc = sdot26(ws_wt, 192 + rr, nx);                      // B1
#pragma unroll
    for (int d = 0; d < 3; d++)
      acc = fmaf(sdot26(ws_wt, rr * 3 + d, nx), zr[d], acc);      // W1
    h1t[rr * BATCH + s] = eluf(acc);
  }
}

// decode phase 2: h2 = elu(W2 h1 + B2)
__global__ __launch_bounds__(64) void kd2(const float* __restrict__ n,
                                          const float* __restrict__ ws_wt,
                                          const float* __restrict__ h1t, float* __restrict__ h2t) {
  int s = blockIdx.x * 64 + threadIdx.x;
  int rb = blockIdx.y * 4;
  float nx[25];
#pragma unroll
  for (int k = 0; k < 25; k++) nx[k] = n[s * 25 + k];
  float acc[4];
#pragma unroll
  for (int r = 0; r < 4; r++) acc[r] = sdot26(ws_wt, 4352 + rb + r, nx);   // B2
  for (int c = 0; c < 64; c++) {
    float h1c = h1t[c * BATCH + s];
#pragma unroll
    for (int r = 0; r < 4; r++) {
      float w = sdot26(ws_wt, 256 + (rb + r) * 64 + c, nx);                // W2
      acc[r] = fmaf(w, h1c, acc[r]);
    }
  }
#pragma unroll
  for (int r = 0; r < 4; r++) h2t[(rb + r) * BATCH + s] = eluf(acc[r]);
}

// decode phase 3: z_hat = W3 h2 + B3, recon partial
__global__ __launch_bounds__(64) void kd3(const float* __restrict__ n,
                                          const float* __restrict__ znext,
                                          const float* __restrict__ ws_wt,
                                          const float* __restrict__ h2t,
                                          float* __restrict__ out, float* __restrict__ accum) {
  int s = blockIdx.x * 64 + threadIdx.x;
  int r = blockIdx.y;
  float nx[25];
#pragma unroll
  for (int k = 0; k < 25; k++) nx[k] = n[s * 25 + k];
  float acc = sdot26(ws_wt, 4608 + r, nx);                                 // B3
  for (int c = 0; c < 64; c++)
    acc = fmaf(sdot26(ws_wt, 4416 + r * 64 + c, nx), h2t[c * BATCH + s], acc); // W3
  out[2 + s * 3 + r] = acc;
  float dz = acc - znext[s * 3 + r];
  float v = dz * dz;
#pragma unroll
  for (int off = 32; off > 0; off >>= 1) v += __shfl_down(v, off, 64);
  if (threadIdx.x == 0) atomicAdd(accum, v);
}

__global__ void k_finish(float* ws, float* __restrict__ out) {
  __shared__ float sred[256];
  int t = threadIdx.x;
  float part = 0.f;
  for (int j = t; j < BATCH; j += 256) {
    float wp2 = ws[WS_WP2 + j];
    float ww2 = ws[WS_WW2 + j];
    float wp = sqrtf(wp2 + 1e-8f);
    float ww = sqrtf(ww2 + 1e-8f);
    part += logf(wp / (ww + 1e-8f) + 1e-8f);
  }
  sred[t] = part; __syncthreads();
  for (int off = 128; off > 0; off >>= 1) { if (t < off) sred[t] += sred[t + off]; __syncthreads(); }
  if (t == 0) {
    float kl = sred[0] / (float)BATCH * (float)D_G + logf((float)BATCH / (float)(BATCH - 1));
    out[0] = ws[WS_ACC] / (float)BATCH;
    out[1] = kl;
  }
}

extern "C" void kernel_launch(void* const* d_in, const int* in_sizes, int n_in,
                              void* d_out, int out_size, void* d_ws, size_t ws_size,
                              hipStream_t stream) {
  (void)in_sizes; (void)n_in; (void)out_size; (void)ws_size;
  const float* z     = (const float*)d_in[0];
  const float* znext = (const float*)d_in[1];
  const float* n     = (const float*)d_in[2];
  const float* prior = (const float*)d_in[3];
  const float* w1W = (const float*)d_in[4];  const float* w1b = (const float*)d_in[5];
  const float* b1W = (const float*)d_in[6];  const float* b1b = (const float*)d_in[7];
  const float* w2W = (const float*)d_in[8];  const float* w2b = (const float*)d_in[9];
  const float* b2W = (const float*)d_in[10]; const float* b2b = (const float*)d_in[11];
  const float* w3W = (const float*)d_in[12]; const float* w3b = (const float*)d_in[13];
  const float* b3W = (const float*)d_in[14]; const float* b3b = (const float*)d_in[15];
  float* out = (float*)d_out;
  float* ws  = (float*)d_ws;

  k_build<<<dim3((KN * D_G + 255) / 256), dim3(256), 0, stream>>>(
      w1W, w1b, b1W, b1b, w2W, w2b, b2W, b2b, w3W, w3b, b3W, b3b, ws);
  k_M<<<dim3(26), dim3(256), 0, stream>>>(ws);
  k_persample<<<dim3(32), dim3(256), 0, stream>>>(n, ws);
  k_prior<<<dim3(512), dim3(256), 0, stream>>>(prior, ws);
  k_pair<<<dim3(8, 64, 2), dim3(256), 0, stream>>>(
      ws + WS_PPAD, ws + WS_RPAD, ws + WS_NT, ws + WS_Q, ws + WS_G2,
      (unsigned int*)(ws + WS_WW2), (unsigned int*)(ws + WS_WP2));
  kd1<<<dim3(128, 4), dim3(64), 0, stream>>>(n, z, ws + WS_WCATT, ws + WS_H1T);
  kd2<<<dim3(128, 16), dim3(64), 0, stream>>>(n, ws + WS_WCATT, ws + WS_H1T, ws + WS_H2T);
  kd3<<<dim3(128, 3), dim3(64), 0, stream>>>(n, znext, ws + WS_WCATT, ws + WS_H2T, out, ws + WS_ACC);
  k_finish<<<dim3(1), dim3(256), 0, stream>>>(ws, out);
}